// Round 4
// baseline (479.620 us; speedup 1.0000x reference)
//
#include <hip/hip_runtime.h>
#include <hip/hip_bf16.h>

#define Bb 2
#define Hh 16
#define Ll 2048
#define Dd 64
#define OUT_ELEMS (Bb*Hh*Ll*Dd)
#define NT (Ll/64)

typedef __attribute__((ext_vector_type(8))) short bf16x8;
typedef __attribute__((ext_vector_type(4))) float f32x4;
typedef __attribute__((ext_vector_type(4))) int i32x4;

__device__ __forceinline__ unsigned short f2bf(float f) {
    union { float f; unsigned int u; } a; a.f = f;
    unsigned int r = a.u + 0x7FFFu + ((a.u >> 16) & 1u);
    return (unsigned short)(r >> 16);
}

// swizzled LDS byte offset: rows are 128B (64 bf16); XOR row bits into the
// 16B-block index to kill ds_read_b128 bank conflicts (G4 / m214 pattern)
__device__ __forceinline__ int swz(int row, int colByte) {
    return row * 128 + (colByte ^ ((row & 7) << 4));
}

__global__ __launch_bounds__(256)
void attn_fused(const float* __restrict__ Q, const float* __restrict__ K,
                const float* __restrict__ V, const int* __restrict__ M,
                const float* __restrict__ Bi, float* __restrict__ out)
{
    __shared__ char Ks[2][64 * 128];   // K tiles, double-buffered
    __shared__ char VTs[2][64 * 128];  // V^T tiles, double-buffered
    __shared__ char Ps[64 * 128];      // P tile (wave-private rows)

    const int bid = blockIdx.x;
    const int b  = bid & 1;           // b innermost: bias-slice users adjacent
    const int qt = (bid >> 1) & 31;
    const int h  = bid >> 6;
    const int q0 = qt * 64;

    const int tid  = threadIdx.x;
    const int w    = tid >> 6;        // wave 0..3
    const int lane = tid & 63;
    const int g    = lane >> 4;
    const int c16  = lane & 15;
    const int qr   = w * 16 + c16;    // this lane's q row (tile-local), fixed

    const float* Qp = Q  + ((size_t)(b * Hh + h) * Ll + q0) * Dd;
    const float* Kp = K  + (size_t)(b * Hh + h) * Ll * Dd;
    const float* Vp = V  + (size_t)(b * Hh + h) * Ll * Dd;
    const int*   Mp = M  + (size_t)b * Ll * Ll + (size_t)q0 * Ll;
    const float* Bp = Bi + (size_t)h * Ll * Ll + (size_t)q0 * Ll;
    float* Op = out + ((size_t)(b * Hh + h) * Ll + q0) * Dd;
    float* Sp = out + OUT_ELEMS + ((size_t)(b * Hh + h) * Ll + q0) * Ll;

    const size_t ro = (size_t)qr * Ll;   // lane's mask/bias/P row offset

    // ---- Q fragments straight into registers (B operand of S^T mfma) ----
    bf16x8 qf[2];
    {
        const float* qrow = Qp + qr * Dd;
#pragma unroll
        for (int kk = 0; kk < 2; ++kk) {
            f32x4 a = *(const f32x4*)(qrow + kk * 32 + g * 8);
            f32x4 c = *(const f32x4*)(qrow + kk * 32 + g * 8 + 4);
            bf16x8 q8;
            q8[0] = (short)f2bf(a[0]); q8[1] = (short)f2bf(a[1]);
            q8[2] = (short)f2bf(a[2]); q8[3] = (short)f2bf(a[3]);
            q8[4] = (short)f2bf(c[0]); q8[5] = (short)f2bf(c[1]);
            q8[6] = (short)f2bf(c[2]); q8[7] = (short)f2bf(c[3]);
            qf[kk] = q8;
        }
    }

    // ---- staging registers (1 tile deep) ----
    float4 kreg[4];
    float  vreg[16];
    i32x4  m4[4];
    f32x4  b4[4];
    const int r0 = tid >> 4, d0 = (tid & 15) * 4;

    auto issueK = [&](int k0) {
#pragma unroll
        for (int rep = 0; rep < 4; ++rep)
            kreg[rep] = *(const float4*)(Kp + (size_t)(k0 + r0 + rep * 16) * Dd + d0);
    };
    auto writeK = [&](char* buf) {
#pragma unroll
        for (int rep = 0; rep < 4; ++rep) {
            int row = r0 + rep * 16;
            ushort4 u = { f2bf(kreg[rep].x), f2bf(kreg[rep].y),
                          f2bf(kreg[rep].z), f2bf(kreg[rep].w) };
            *(ushort4*)(buf + swz(row, d0 * 2)) = u;
        }
    };
    auto issueV = [&](int k0) {
#pragma unroll
        for (int r = 0; r < 4; ++r)
#pragma unroll
            for (int i = 0; i < 4; ++i)
                vreg[r * 4 + i] = Vp[(size_t)(k0 + w * 16 + r * 4 + i) * Dd + lane];
    };
    auto writeV = [&](char* buf) {    // transposed: buf[d][k]
#pragma unroll
        for (int r = 0; r < 4; ++r) {
            ushort4 u = { f2bf(vreg[r * 4 + 0]), f2bf(vreg[r * 4 + 1]),
                          f2bf(vreg[r * 4 + 2]), f2bf(vreg[r * 4 + 3]) };
            *(ushort4*)(buf + swz(lane, (w * 16 + r * 4) * 2)) = u;
        }
    };
    auto issueMB = [&](int k0) {
#pragma unroll
        for (int ct = 0; ct < 4; ++ct) {
            m4[ct] = *(const i32x4*)(Mp + ro + k0 + ct * 16 + g * 4);
            b4[ct] = *(const f32x4*)(Bp + ro + k0 + ct * 16 + g * 4);
        }
    };

    // S^T tile: sacc[ct][r] = S[k0 + ct*16 + g*4 + r][q0 + qr]
    auto mfmaST = [&](const char* kbuf, f32x4 (&sacc)[4]) {
#pragma unroll
        for (int kk = 0; kk < 2; ++kk) {
#pragma unroll
            for (int ct = 0; ct < 4; ++ct) {
                bf16x8 af = *(const bf16x8*)(kbuf + swz(ct * 16 + c16, kk * 64 + g * 16));
                sacc[ct] = __builtin_amdgcn_mfma_f32_16x16x32_bf16(af, qf[kk], sacc[ct], 0, 0, 0);
            }
        }
    };

    // ================= sweep 1: per-q-row sums of exp(S) =================
    issueK(0);
    issueMB(0);
    writeK(Ks[0]);                    // waits tile0 loads (once, prologue)
    issueK(64);                       // kreg <- tile1
    __syncthreads();
    float rsv[4] = {0.f, 0.f, 0.f, 0.f};
    for (int t = 0; t < NT; ++t) {
        f32x4 sacc[4] = {{0,0,0,0},{0,0,0,0},{0,0,0,0},{0,0,0,0}};
        mfmaST(Ks[t & 1], sacc);
#pragma unroll
        for (int ct = 0; ct < 4; ++ct)
#pragma unroll
            for (int r = 0; r < 4; ++r) {
                float s = sacc[ct][r] * 0.125f;
                s = (m4[ct][r] == 0 ? -10000.0f : s) + b4[ct][r];
                rsv[ct] += __expf(s);
            }
        writeK(Ks[(t + 1) & 1]);      // tile t+1 (vmcnt shadowed by compute)
        issueK(((t + 2) & (NT - 1)) * 64);   // wrap: warms sweep-2 tiles 0,1
        issueMB(((t + 1) & (NT - 1)) * 64);  // after last use of m4/b4
        __syncthreads();              // publishes Ks[(t+1)&1]
    }
    float rs = (rsv[0] + rsv[1]) + (rsv[2] + rsv[3]);
    rs += __shfl_xor(rs, 16);
    rs += __shfl_xor(rs, 32);
    const float inv = 1.0f / rs;

    // handoff state: Ks[0]=tile0, kreg=tile1, m4/b4=tile0
    issueV(0);
    writeV(VTs[0]);                   // exposed wait once, negligible
    issueV(64);                       // vreg <- tile1
    __syncthreads();

    // ====== sweep 2: recompute S^T, write P fp32 (vec4, NT), O = P·V ======
    f32x4 oacc[4] = {{0,0,0,0},{0,0,0,0},{0,0,0,0},{0,0,0,0}};
    for (int t = 0; t < NT; ++t) {
        f32x4 sacc[4] = {{0,0,0,0},{0,0,0,0},{0,0,0,0},{0,0,0,0}};
        mfmaST(Ks[t & 1], sacc);
        const int k0 = t * 64;
#pragma unroll
        for (int ct = 0; ct < 4; ++ct) {
            f32x4 p;
#pragma unroll
            for (int r = 0; r < 4; ++r) {
                float s = sacc[ct][r] * 0.125f;
                s = (m4[ct][r] == 0 ? -10000.0f : s) + b4[ct][r];
                p[r] = __expf(s) * inv;
            }
            __builtin_nontemporal_store(p, (f32x4*)(Sp + ro + k0 + ct * 16 + g * 4));
            ushort4 u = { (unsigned short)f2bf(p[0]), (unsigned short)f2bf(p[1]),
                          (unsigned short)f2bf(p[2]), (unsigned short)f2bf(p[3]) };
            *(ushort4*)(Ps + swz(qr, ct * 32 + g * 8)) = u;   // own-wave rows only
        }
        // PV: Ps rows are wave-private → no barrier needed before reading
#pragma unroll
        for (int kk = 0; kk < 2; ++kk) {
            bf16x8 pf = *(const bf16x8*)(Ps + swz(qr, kk * 64 + g * 16));
#pragma unroll
            for (int dt = 0; dt < 4; ++dt) {
                bf16x8 vf = *(const bf16x8*)(VTs[t & 1] + swz(dt * 16 + c16, kk * 64 + g * 16));
                oacc[dt] = __builtin_amdgcn_mfma_f32_16x16x32_bf16(pf, vf, oacc[dt], 0, 0, 0);
            }
        }
        if (t + 1 < NT) {             // stage tile t+1 (vmcnt shadowed above)
            writeK(Ks[(t + 1) & 1]);
            writeV(VTs[(t + 1) & 1]);
            issueMB((t + 1) * 64);
        }
        if (t + 2 < NT) {             // refill regs with tile t+2
            issueK((t + 2) * 64);
            issueV((t + 2) * 64);
        }
        __syncthreads();
    }

    // ---- write O (already normalized; C rows = q = w*16 + g*4 + r) ----
#pragma unroll
    for (int dt = 0; dt < 4; ++dt)
#pragma unroll
        for (int r = 0; r < 4; ++r)
            Op[(w * 16 + g * 4 + r) * Dd + dt * 16 + c16] = oacc[dt][r];
}

extern "C" void kernel_launch(void* const* d_in, const int* in_sizes, int n_in,
                              void* d_out, int out_size, void* d_ws, size_t ws_size,
                              hipStream_t stream) {
    const float* Q  = (const float*)d_in[0];
    const float* K  = (const float*)d_in[1];
    const float* V  = (const float*)d_in[2];
    const int*   M  = (const int*)d_in[3];
    const float* Bi = (const float*)d_in[4];
    float* out = (float*)d_out;

    dim3 grid(Bb * Hh * (Ll / 64));   // 1024 blocks: b innermost, then qt, h
    dim3 block(256);
    attn_fused<<<grid, block, 0, stream>>>(Q, K, V, M, Bi, out);
}

// Round 5
// 478.698 us; speedup vs baseline: 1.0019x; 1.0019x over previous
//
#include <hip/hip_runtime.h>
#include <hip/hip_bf16.h>

#define Bb 2
#define Hh 16
#define Ll 2048
#define Dd 64
#define OUT_ELEMS (Bb*Hh*Ll*Dd)
#define NT (Ll/64)

typedef __attribute__((ext_vector_type(8))) short bf16x8;
typedef __attribute__((ext_vector_type(4))) float f32x4;
typedef __attribute__((ext_vector_type(4))) int i32x4;

// HW packed conversion: 1 VALU op for 2 bf16 (RTNE), replaces 8-op bit trick
__device__ __forceinline__ unsigned int pk2(float a, float b) {
    unsigned int r;
    asm("v_cvt_pk_bf16_f32 %0, %1, %2" : "=v"(r) : "v"(a), "v"(b));
    return r;
}

// swizzled LDS byte offset: rows are 128B (64 bf16); XOR row bits into the
// 16B-block index to kill ds_read_b128 bank conflicts (G4 / m214 pattern)
__device__ __forceinline__ int swz(int row, int colByte) {
    return row * 128 + (colByte ^ ((row & 7) << 4));
}

__global__ __launch_bounds__(256)
void attn_fused(const float* __restrict__ Q, const float* __restrict__ K,
                const float* __restrict__ V, const int* __restrict__ M,
                const float* __restrict__ Bi, float* __restrict__ out)
{
    __shared__ char Ks[2][64 * 128];   // K tiles, double-buffered
    __shared__ char VTs[2][64 * 128];  // V^T tiles, double-buffered
    __shared__ char Ps[64 * 128];      // P tile (wave-private rows)

    const int bid = blockIdx.x;
    const int b  = bid & 1;           // b innermost: bias-slice users adjacent
    const int qt = (bid >> 1) & 31;
    const int h  = bid >> 6;
    const int q0 = qt * 64;

    const int tid  = threadIdx.x;
    const int w    = tid >> 6;        // wave 0..3
    const int lane = tid & 63;
    const int g    = lane >> 4;
    const int c16  = lane & 15;
    const int qr   = w * 16 + c16;    // this lane's q row (tile-local), fixed

    const float* Qp = Q  + ((size_t)(b * Hh + h) * Ll + q0) * Dd;
    const float* Kp = K  + (size_t)(b * Hh + h) * Ll * Dd;
    const float* Vp = V  + (size_t)(b * Hh + h) * Ll * Dd;
    float* Op = out + ((size_t)(b * Hh + h) * Ll + q0) * Dd;

    // per-lane row pointers (hoisted: strength-reduced by k0 below)
    const int*   mrow = M  + (size_t)b * Ll * Ll + ((size_t)q0 + qr) * Ll;
    const float* brow = Bi + (size_t)h * Ll * Ll + ((size_t)q0 + qr) * Ll;
    float*       srow = out + OUT_ELEMS + ((size_t)(b * Hh + h) * Ll + q0 + qr) * Ll;

    // ---- Q fragments straight into registers (B operand of S^T mfma) ----
    bf16x8 qf[2];
    {
        const float* qrow = Qp + qr * Dd;
#pragma unroll
        for (int kk = 0; kk < 2; ++kk) {
            f32x4 a = *(const f32x4*)(qrow + kk * 32 + g * 8);
            f32x4 c = *(const f32x4*)(qrow + kk * 32 + g * 8 + 4);
            union { bf16x8 v; unsigned int u[4]; } cvt;
            cvt.u[0] = pk2(a[0], a[1]); cvt.u[1] = pk2(a[2], a[3]);
            cvt.u[2] = pk2(c[0], c[1]); cvt.u[3] = pk2(c[2], c[3]);
            qf[kk] = cvt.v;
        }
    }

    // ---- staging registers (1 tile deep) ----
    float4 kreg[4];
    float  vreg[16];
    i32x4  m4[4];
    f32x4  b4[4];
    const int r0 = tid >> 4, d0 = (tid & 15) * 4;

    auto issueK = [&](int k0) {
#pragma unroll
        for (int rep = 0; rep < 4; ++rep)
            kreg[rep] = *(const float4*)(Kp + (size_t)(k0 + r0 + rep * 16) * Dd + d0);
    };
    auto writeK = [&](char* buf) {
#pragma unroll
        for (int rep = 0; rep < 4; ++rep) {
            uint2 u = { pk2(kreg[rep].x, kreg[rep].y), pk2(kreg[rep].z, kreg[rep].w) };
            *(uint2*)(buf + swz(r0 + rep * 16, d0 * 2)) = u;
        }
    };
    auto issueV = [&](int k0) {
#pragma unroll
        for (int r = 0; r < 4; ++r)
#pragma unroll
            for (int i = 0; i < 4; ++i)
                vreg[r * 4 + i] = Vp[(size_t)(k0 + w * 16 + r * 4 + i) * Dd + lane];
    };
    auto writeV = [&](char* buf) {    // transposed: buf[d][k]
#pragma unroll
        for (int r = 0; r < 4; ++r) {
            uint2 u = { pk2(vreg[r * 4 + 0], vreg[r * 4 + 1]),
                        pk2(vreg[r * 4 + 2], vreg[r * 4 + 3]) };
            *(uint2*)(buf + swz(lane, (w * 16 + r * 4) * 2)) = u;
        }
    };
    auto issueMB = [&](int k0) {
#pragma unroll
        for (int ct = 0; ct < 4; ++ct) {
            m4[ct] = *(const i32x4*)(mrow + k0 + ct * 16 + g * 4);
            b4[ct] = *(const f32x4*)(brow + k0 + ct * 16 + g * 4);
        }
    };

    // S^T tile: sacc[ct][r] = S[k0 + ct*16 + g*4 + r][q0 + qr]
    auto mfmaST = [&](const char* kbuf, f32x4 (&sacc)[4]) {
        __builtin_amdgcn_s_setprio(1);
#pragma unroll
        for (int kk = 0; kk < 2; ++kk) {
#pragma unroll
            for (int ct = 0; ct < 4; ++ct) {
                bf16x8 af = *(const bf16x8*)(kbuf + swz(ct * 16 + c16, kk * 64 + g * 16));
                sacc[ct] = __builtin_amdgcn_mfma_f32_16x16x32_bf16(af, qf[kk], sacc[ct], 0, 0, 0);
            }
        }
        __builtin_amdgcn_s_setprio(0);
    };

    // ================= sweep 1: per-q-row sums of exp(S) =================
    issueK(0);
    issueMB(0);
    writeK(Ks[0]);                    // waits tile0 loads (once, prologue)
    issueK(64);                       // kreg <- tile1
    __syncthreads();
    float rsv[4] = {0.f, 0.f, 0.f, 0.f};
    for (int t = 0; t < NT; ++t) {
        f32x4 sacc[4] = {{0,0,0,0},{0,0,0,0},{0,0,0,0},{0,0,0,0}};
        mfmaST(Ks[t & 1], sacc);
#pragma unroll
        for (int ct = 0; ct < 4; ++ct)
#pragma unroll
            for (int r = 0; r < 4; ++r) {
                float s = m4[ct][r] == 0 ? -10000.0f
                                         : fmaf(sacc[ct][r], 0.125f, b4[ct][r]);
                rsv[ct] += __expf(s);
            }
        writeK(Ks[(t + 1) & 1]);      // tile t+1 (vmcnt shadowed by compute)
        issueK(((t + 2) & (NT - 1)) * 64);   // wrap: warms sweep-2 tiles 0,1
        issueMB(((t + 1) & (NT - 1)) * 64);  // after last use of m4/b4
        __syncthreads();              // publishes Ks[(t+1)&1]
    }
    float rs = (rsv[0] + rsv[1]) + (rsv[2] + rsv[3]);
    rs += __shfl_xor(rs, 16);
    rs += __shfl_xor(rs, 32);
    const float inv = 1.0f / rs;

    // handoff state: Ks[0]=tile0, kreg=tile1, m4/b4=tile0
    issueV(0);
    writeV(VTs[0]);                   // exposed wait once, negligible
    issueV(64);                       // vreg <- tile1
    __syncthreads();

    // ====== sweep 2: recompute S^T, write P fp32 (vec4, NT), O = P·V ======
    f32x4 oacc[4] = {{0,0,0,0},{0,0,0,0},{0,0,0,0},{0,0,0,0}};
    for (int t = 0; t < NT; ++t) {
        f32x4 sacc[4] = {{0,0,0,0},{0,0,0,0},{0,0,0,0},{0,0,0,0}};
        mfmaST(Ks[t & 1], sacc);
        const int k0 = t * 64;
#pragma unroll
        for (int ct = 0; ct < 4; ++ct) {
            f32x4 p;
#pragma unroll
            for (int r = 0; r < 4; ++r) {
                float s = m4[ct][r] == 0 ? -10000.0f
                                         : fmaf(sacc[ct][r], 0.125f, b4[ct][r]);
                p[r] = __expf(s) * inv;
            }
            __builtin_nontemporal_store(p, (f32x4*)(srow + k0 + ct * 16 + g * 4));
            uint2 u = { pk2(p[0], p[1]), pk2(p[2], p[3]) };
            *(uint2*)(Ps + swz(qr, ct * 32 + g * 8)) = u;   // own-wave rows only
        }
        // PV: Ps rows are wave-private → no barrier needed before reading
        __builtin_amdgcn_s_setprio(1);
#pragma unroll
        for (int kk = 0; kk < 2; ++kk) {
            bf16x8 pf = *(const bf16x8*)(Ps + swz(qr, kk * 64 + g * 16));
#pragma unroll
            for (int dt = 0; dt < 4; ++dt) {
                bf16x8 vf = *(const bf16x8*)(VTs[t & 1] + swz(dt * 16 + c16, kk * 64 + g * 16));
                oacc[dt] = __builtin_amdgcn_mfma_f32_16x16x32_bf16(pf, vf, oacc[dt], 0, 0, 0);
            }
        }
        __builtin_amdgcn_s_setprio(0);
        if (t + 1 < NT) {             // stage tile t+1 (vmcnt shadowed above)
            writeK(Ks[(t + 1) & 1]);
            writeV(VTs[(t + 1) & 1]);
            issueMB((t + 1) * 64);
        }
        if (t + 2 < NT) {             // refill regs with tile t+2
            issueK((t + 2) * 64);
            issueV((t + 2) * 64);
        }
        __syncthreads();
    }

    // ---- write O (already normalized; C rows = q = w*16 + g*4 + r) ----
#pragma unroll
    for (int dt = 0; dt < 4; ++dt)
#pragma unroll
        for (int r = 0; r < 4; ++r)
            Op[(w * 16 + g * 4 + r) * Dd + dt * 16 + c16] = oacc[dt][r];
}

extern "C" void kernel_launch(void* const* d_in, const int* in_sizes, int n_in,
                              void* d_out, int out_size, void* d_ws, size_t ws_size,
                              hipStream_t stream) {
    const float* Q  = (const float*)d_in[0];
    const float* K  = (const float*)d_in[1];
    const float* V  = (const float*)d_in[2];
    const int*   M  = (const int*)d_in[3];
    const float* Bi = (const float*)d_in[4];
    float* out = (float*)d_out;

    dim3 grid(Bb * Hh * (Ll / 64));   // 1024 blocks: b innermost, then qt, h
    dim3 block(256);
    attn_fused<<<grid, block, 0, stream>>>(Q, K, V, M, Bi, out);
}